// Round 12
// baseline (1908.110 us; speedup 1.0000x reference)
//
#include <hip/hip_runtime.h>
#include <hip/hip_bf16.h>

#define DIM_K 4096
#define DIM_N 4096
#define M_TOK 8192

typedef __attribute__((ext_vector_type(8))) short bf16x8;
typedef __attribute__((ext_vector_type(4))) float f32x4;

typedef const __attribute__((address_space(1))) unsigned int gu32;
typedef __attribute__((address_space(3))) unsigned int lu32;

__device__ __forceinline__ unsigned short f2bf(float f) {
  unsigned int u = __float_as_uint(f);
  u += 0x7FFFu + ((u >> 16) & 1u);   // round-to-nearest-even
  return (unsigned short)(u >> 16);
}

__device__ __forceinline__ void gload_lds16(const void* g, void* l) {
  __builtin_amdgcn_global_load_lds((gu32*)g, (lu32*)l, 16, 0, 0);
}

// ---------------- pre-pass 1: x fp32 [M][K] -> bf16 [M][K] ----------------
__global__ void cvt_x_kernel(const float* __restrict__ x,
                             unsigned short* __restrict__ xb, int n4) {
  int idx = blockIdx.x * blockDim.x + threadIdx.x;
  int stride = gridDim.x * blockDim.x;
  for (int i = idx; i < n4; i += stride) {
    float4 v = reinterpret_cast<const float4*>(x)[i];
    ushort4 o;
    o.x = f2bf(v.x); o.y = f2bf(v.y); o.z = f2bf(v.z); o.w = f2bf(v.w);
    reinterpret_cast<ushort4*>(xb)[i] = o;
  }
}

// ---------- pre-pass 2: W fp32 [K][N] -> Wt bf16 [N][K] (transpose) --------
// Staircase-aware: blocks fully inside the zero region exit immediately.
__global__ void cvt_wt_kernel(const float* __restrict__ W,
                              unsigned short* __restrict__ Wt) {
  __shared__ unsigned short tile[32][33];
  const int k0 = blockIdx.x * 32;
  const int n0 = blockIdx.y * 32;
  const int kendn = (n0 < 1024) ? 1024 : (n0 < 2048 ? 2048 : 4096);
  if (k0 >= kendn) return;
  const int tx = threadIdx.x;  // 0..31
  const int ty = threadIdx.y;  // 0..7
#pragma unroll
  for (int j = 0; j < 4; ++j) {
    int k = k0 + ty + 8 * j;
    tile[ty + 8 * j][tx] = f2bf(W[(size_t)k * DIM_N + n0 + tx]);
  }
  __syncthreads();
#pragma unroll
  for (int j = 0; j < 4; ++j) {
    int n = n0 + ty + 8 * j;
    Wt[(size_t)n * DIM_K + k0 + tx] = tile[tx][ty + 8 * j];
  }
}

// ---------------------------------------------------------------------------
// 256x256-tile GEMM, C = A * Bt^T, bf16 MFMA 16x16x32.
// KEY CHANGE vs R4: 2-deep LDS double-buffer (64 KB) => 2 BLOCKS/CU
// (16 waves/CU). All R2-R11 schedules ran 1 block/CU and measured LDS+MFMA
// SUM (~2470 cyc/K-tile): a single barrier-locked block has no co-resident
// work to fill its vmcnt/barrier drains. With 2 blocks/CU, block A's drain
// overlaps block B's MFMA cluster (m114 mechanism; m97's 912TF had 3/CU).
// Loop = proven m97 single-barrier form (no read skew):
//   iter k: STAGE(k+1 -> buf (k+1)&1); READF(cur=k&1); MFMA; vmcnt(0); barrier
// RAW: reads of cur staged in iter k-1, drained by its vmcnt(0)+barrier.
// WAR: STAGE(k+1) overwrites buf whose frags were consumed by MFMA(k-1)
// (compiler lgkm-waits before use) before the iter k-1 barrier.
// __launch_bounds__(512,4) caps VGPR at 128 = exact 16-wave/CU budget.
// Heavy-first ordering: bids 0-255 heavy => CU pairs ~ {heavy, mid/light}.
// ---------------------------------------------------------------------------
__global__ __launch_bounds__(512, 4) void gemm_kernel(
    const unsigned short* __restrict__ A,   // [M][K] bf16
    const unsigned short* __restrict__ Bt,  // [N][K] bf16
    float* __restrict__ C) {
  __shared__ unsigned short lds[32768];  // 64 KB: 2 bufs x (A 16KB + B 16KB)

  const int tid = threadIdx.x;
  const int lane = tid & 63;
  const int w = tid >> 6;   // 0..7
  const int wr = w >> 2;    // 0..1 : M half (128 rows)
  const int wc = w & 3;     // 0..3 : N quarter (64 cols)

  const int bid = blockIdx.x;
  const int bx = bid & 31;
  const int by = 15 - (bid >> 5);    // heavy (kend=4096) first: bids 0-255
  const int m0 = bx * 256;
  const int n0 = by * 256;
  const int kend = (n0 < 1024) ? 1024 : (n0 < 2048 ? 2048 : 4096);
  const int nk = kend >> 5;          // K-tiles of 32: 32 / 64 / 128

  const unsigned short* Ab = A + (size_t)m0 * DIM_K;
  const unsigned short* Bb = Bt + (size_t)n0 * DIM_K;

  // --- staging geometry (R4-proven): linear LDS dest, inverse-swizzled
  //     global source. slot_k = k ^ (((row>>1)&3)<<3) in element space.
  int srcoff[2];
#pragma unroll
  for (int i = 0; i < 2; ++i) {
    int L = i * 8192 + w * 1024 + lane * 16;   // byte offset in 16KB region
    int r = L >> 6;                            // row (64B rows), 0..255
    int kc = (L >> 4) & 3;
    int ks = (kc ^ ((r >> 1) & 3)) << 3;
    srcoff[i] = r * DIM_K + ks;
  }
  const int dstoff0 = w * 512;           // shorts, wave-uniform
  const int dstoff1 = 4096 + w * 512;

  // --- fragment geometry (16x16x32: row/col = lane&15, k=(lane>>4)*8+j)
  const int l15 = lane & 15;
  const int kb = (lane >> 4) << 3;
  const int rA = wr * 128 + l15;
  const int rB = wc * 64 + l15;
  const int koffA = kb ^ (((rA >> 1) & 3) << 3);
  const int koffB = kb ^ (((rB >> 1) & 3) << 3);

#define AFRAG(bufc, mi) (*reinterpret_cast<const bf16x8*>( \
    &lds[(bufc)*16384 + (rA + (mi)*16)*32 + koffA]))
#define BFRAG(bufc, ni) (*reinterpret_cast<const bf16x8*>( \
    &lds[(bufc)*16384 + 8192 + (rB + (ni)*16)*32 + koffB]))

#define STAGE(kt, bufc)                                                        \
  do {                                                                         \
    gload_lds16(Ab + (size_t)(kt) * 32 + srcoff[0], &lds[(bufc)*16384 + dstoff0]); \
    gload_lds16(Ab + (size_t)(kt) * 32 + srcoff[1], &lds[(bufc)*16384 + dstoff1]); \
    gload_lds16(Bb + (size_t)(kt) * 32 + srcoff[0], &lds[(bufc)*16384 + 8192 + dstoff0]); \
    gload_lds16(Bb + (size_t)(kt) * 32 + srcoff[1], &lds[(bufc)*16384 + 8192 + dstoff1]); \
  } while (0)

#define READF(Af, Bf, bufc)                                                    \
  do {                                                                         \
    _Pragma("unroll") for (int mi = 0; mi < 8; ++mi) Af[mi] = AFRAG(bufc, mi); \
    _Pragma("unroll") for (int ni = 0; ni < 4; ++ni) Bf[ni] = BFRAG(bufc, ni); \
  } while (0)

#define MFMA32(Af, Bf)                                                         \
  do {                                                                         \
    __builtin_amdgcn_s_setprio(1);                                             \
    _Pragma("unroll") for (int mi = 0; mi < 8; ++mi)                           \
      _Pragma("unroll") for (int ni = 0; ni < 4; ++ni)                         \
        acc[mi][ni] = __builtin_amdgcn_mfma_f32_16x16x32_bf16(                 \
            Af[mi], Bf[ni], acc[mi][ni], 0, 0, 0);                             \
    __builtin_amdgcn_s_setprio(0);                                             \
  } while (0)

  f32x4 acc[8][4];
#pragma unroll
  for (int i = 0; i < 8; ++i)
#pragma unroll
    for (int j = 0; j < 4; ++j) acc[i][j] = (f32x4){0.f, 0.f, 0.f, 0.f};

  bf16x8 A0[8], B0[4];

  // --- prologue: stage tile 0 into buf 0
  STAGE(0, 0);
  asm volatile("s_waitcnt vmcnt(0)" ::: "memory");
  __builtin_amdgcn_s_barrier();

  // --- main loop: one barrier per K-tile; 2-deep ping-pong buffers
  for (int k = 0; k < nk; ++k) {
    const int cur = k & 1;
    const int kt = (k + 1 < nk) ? (k + 1) : (nk - 1);
    STAGE(kt, cur ^ 1);                  // issue next-tile loads early
    READF(A0, B0, cur);                  // ds_reads of resident tile
    MFMA32(A0, B0);                      // compute (compiler lgkm-waits)
    asm volatile("s_waitcnt vmcnt(0)" ::: "memory");  // next tile landed
    __builtin_amdgcn_s_barrier();
  }

  // --- epilogue: C/D layout col=lane&15, row=(lane>>4)*4+reg
  const int crow0 = m0 + wr * 128 + (lane >> 4) * 4;
  const int ccol0 = n0 + wc * 64 + l15;
#pragma unroll
  for (int mi = 0; mi < 8; ++mi)
#pragma unroll
    for (int ni = 0; ni < 4; ++ni) {
      float* Cp = C + (size_t)(crow0 + mi * 16) * DIM_N + ccol0 + ni * 16;
#pragma unroll
      for (int r2 = 0; r2 < 4; ++r2) Cp[(size_t)r2 * DIM_N] = acc[mi][ni][r2];
    }
#undef AFRAG
#undef BFRAG
#undef STAGE
#undef READF
#undef MFMA32
}

extern "C" void kernel_launch(void* const* d_in, const int* in_sizes, int n_in,
                              void* d_out, int out_size, void* d_ws,
                              size_t ws_size, hipStream_t stream) {
  const float* x = (const float*)d_in[0];
  const float* W = (const float*)d_in[1];
  float* out = (float*)d_out;

  unsigned short* xb = (unsigned short*)d_ws;                  // 64 MB
  unsigned short* wt = xb + (size_t)M_TOK * DIM_K;             // 32 MB

  cvt_x_kernel<<<2048, 256, 0, stream>>>(x, xb, M_TOK * DIM_K / 4);
  cvt_wt_kernel<<<dim3(DIM_K / 32, DIM_N / 32), dim3(32, 8), 0, stream>>>(W, wt);
  gemm_kernel<<<512, 512, 0, stream>>>(xb, wt, out);
}

// Round 13
// 231.121 us; speedup vs baseline: 8.2559x; 8.2559x over previous
//
#include <hip/hip_runtime.h>
#include <hip/hip_bf16.h>

#define DIM_K 4096
#define DIM_N 4096
#define M_TOK 8192

typedef __attribute__((ext_vector_type(8))) short bf16x8;
typedef __attribute__((ext_vector_type(4))) float f32x4;

typedef const __attribute__((address_space(1))) unsigned int gu32;
typedef __attribute__((address_space(3))) unsigned int lu32;

__device__ __forceinline__ unsigned short f2bf(float f) {
  unsigned int u = __float_as_uint(f);
  u += 0x7FFFu + ((u >> 16) & 1u);   // round-to-nearest-even
  return (unsigned short)(u >> 16);
}

__device__ __forceinline__ void gload_lds16(const void* g, void* l) {
  __builtin_amdgcn_global_load_lds((gu32*)g, (lu32*)l, 16, 0, 0);
}

// ---------------- pre-pass 1: x fp32 [M][K] -> bf16 [M][K] ----------------
__global__ void cvt_x_kernel(const float* __restrict__ x,
                             unsigned short* __restrict__ xb, int n4) {
  int idx = blockIdx.x * blockDim.x + threadIdx.x;
  int stride = gridDim.x * blockDim.x;
  for (int i = idx; i < n4; i += stride) {
    float4 v = reinterpret_cast<const float4*>(x)[i];
    ushort4 o;
    o.x = f2bf(v.x); o.y = f2bf(v.y); o.z = f2bf(v.z); o.w = f2bf(v.w);
    reinterpret_cast<ushort4*>(xb)[i] = o;
  }
}

// ---------- pre-pass 2: W fp32 [K][N] -> Wt bf16 [N][K] (transpose) --------
// Staircase-aware: blocks fully inside the zero region exit immediately.
__global__ void cvt_wt_kernel(const float* __restrict__ W,
                              unsigned short* __restrict__ Wt) {
  __shared__ unsigned short tile[32][33];
  const int k0 = blockIdx.x * 32;
  const int n0 = blockIdx.y * 32;
  const int kendn = (n0 < 1024) ? 1024 : (n0 < 2048 ? 2048 : 4096);
  if (k0 >= kendn) return;
  const int tx = threadIdx.x;  // 0..31
  const int ty = threadIdx.y;  // 0..7
#pragma unroll
  for (int j = 0; j < 4; ++j) {
    int k = k0 + ty + 8 * j;
    tile[ty + 8 * j][tx] = f2bf(W[(size_t)k * DIM_N + n0 + tx]);
  }
  __syncthreads();
#pragma unroll
  for (int j = 0; j < 4; ++j) {
    int n = n0 + ty + 8 * j;
    Wt[(size_t)n * DIM_K + k0 + tx] = tile[tx][ty + 8 * j];
  }
}

// ---------------------------------------------------------------------------
// 256x256-tile GEMM, C = A * Bt^T, bf16 MFMA 16x16x32 — R4 (proven 181us)
// plus ONE sched_barrier(0) per iteration.
// Diagnosis: R4's textual order {READF(k+1); STAGE; MFMA(k)} is re-serialized
// by the compiler sinking the prefetch ds_reads to their use (next iter's
// MFMA) -> every iter pays read-drain THEN MFMA (sum, 2328 cyc/K-tile).
// The single sched_barrier(0) pins reads+stages ABOVE the MFMA cluster so
// their drain overlaps the 1242-cyc MFMA pipe work. No other changes.
// Ring safety (R4-proven): reads of buf[(k+1)&3]; STAGE targets buf[(k+3)&3]
// (disjoint from in-flight reads by design => no extra lgkm needed);
// trailing vmcnt(4) drains iter k-1's stage before the barrier => RAW-safe.
// ---------------------------------------------------------------------------
__global__ __launch_bounds__(512, 2) void gemm_kernel(
    const unsigned short* __restrict__ A,   // [M][K] bf16
    const unsigned short* __restrict__ Bt,  // [N][K] bf16
    float* __restrict__ C) {
  __shared__ unsigned short lds[65536];  // 128 KB = 4 bufs x (A 8K + B 8K shorts)

  const int tid = threadIdx.x;
  const int lane = tid & 63;
  const int w = tid >> 6;   // 0..7
  const int wr = w >> 2;    // 0..1 : M half (128 rows)
  const int wc = w & 3;     // 0..3 : N quarter (64 cols)

  const int bid = blockIdx.x;
  const int bx = bid & 31;           // m-tile
  const int by = 15 - (bid >> 5);    // n-tile; heavy (kend=4096) first
  const int m0 = bx * 256;
  const int n0 = by * 256;
  const int kend = (n0 < 1024) ? 1024 : (n0 < 2048 ? 2048 : 4096);
  const int nk = kend >> 5;          // K-tiles of 32 (32 / 64 / 128)

  const unsigned short* Ab = A + (size_t)m0 * DIM_K;
  const unsigned short* Bb = Bt + (size_t)n0 * DIM_K;

  // --- staging geometry (proven): linear LDS dest, inverse-swizzled global
  //     source. slot_k = k ^ (((row>>1)&3)<<3) in element space.
  int srcoff[2];
#pragma unroll
  for (int i = 0; i < 2; ++i) {
    int L = i * 8192 + w * 1024 + lane * 16;
    int r = L >> 6;
    int kc = (L >> 4) & 3;
    int ks = (kc ^ ((r >> 1) & 3)) << 3;
    srcoff[i] = r * DIM_K + ks;
  }
  const int dstoff0 = w * 512;           // shorts, wave-uniform
  const int dstoff1 = 4096 + w * 512;

  // --- fragment read geometry (16x16x32: row/col = lane&15, k=(lane>>4)*8+j)
  const int l15 = lane & 15;
  const int kb = (lane >> 4) << 3;
  const int rA = wr * 128 + l15;
  const int rB = wc * 64 + l15;
  const int koffA = kb ^ (((rA >> 1) & 3) << 3);
  const int koffB = kb ^ (((rB >> 1) & 3) << 3);

#define AFRAG(bufc, mi) \
  (*reinterpret_cast<const bf16x8*>(&lds[(bufc)*16384 + (rA + (mi)*16)*32 + koffA]))
#define BFRAG(bufc, ni) \
  (*reinterpret_cast<const bf16x8*>(&lds[(bufc)*16384 + 8192 + (rB + (ni)*16)*32 + koffB]))

#define STAGE(kt, bufc)                                                        \
  do {                                                                         \
    gload_lds16(Ab + (size_t)(kt) * 32 + srcoff[0], &lds[(bufc)*16384 + dstoff0]); \
    gload_lds16(Ab + (size_t)(kt) * 32 + srcoff[1], &lds[(bufc)*16384 + dstoff1]); \
    gload_lds16(Bb + (size_t)(kt) * 32 + srcoff[0], &lds[(bufc)*16384 + 8192 + dstoff0]); \
    gload_lds16(Bb + (size_t)(kt) * 32 + srcoff[1], &lds[(bufc)*16384 + 8192 + dstoff1]); \
  } while (0)

#define READF(Af, Bf, bufc)                                                    \
  do {                                                                         \
    _Pragma("unroll") for (int mi = 0; mi < 8; ++mi) Af[mi] = AFRAG(bufc, mi); \
    _Pragma("unroll") for (int ni = 0; ni < 4; ++ni) Bf[ni] = BFRAG(bufc, ni); \
  } while (0)

#define MFMA32(Af, Bf)                                                         \
  do {                                                                         \
    __builtin_amdgcn_s_setprio(1);                                             \
    _Pragma("unroll") for (int mi = 0; mi < 8; ++mi)                           \
      _Pragma("unroll") for (int ni = 0; ni < 4; ++ni)                         \
        acc[mi][ni] = __builtin_amdgcn_mfma_f32_16x16x32_bf16(                 \
            Af[mi], Bf[ni], acc[mi][ni], 0, 0, 0);                             \
    __builtin_amdgcn_s_setprio(0);                                             \
  } while (0)

  f32x4 acc[8][4];
#pragma unroll
  for (int i = 0; i < 8; ++i)
#pragma unroll
    for (int j = 0; j < 4; ++j) acc[i][j] = (f32x4){0.f, 0.f, 0.f, 0.f};

  bf16x8 A0[8], B0[4], A1[8], B1[4];

  // --- prologue: stage tiles 0,1,2 ; ensure buf0 then buf1 resident
  STAGE(0, 0);
  STAGE(1, 1);
  STAGE(2, 2);
  asm volatile("s_waitcnt vmcnt(8)" ::: "memory");  // stage(0) complete
  __builtin_amdgcn_s_barrier();
  READF(A0, B0, 0);                                  // preload tile 0 frags
  asm volatile("s_waitcnt vmcnt(4)" ::: "memory");  // stage(1) complete
  __builtin_amdgcn_s_barrier();

  // --- main loop: one barrier per k-tile, ping-pong frag regs (static idx).
  //     The single sched_barrier(0) pins {reads(k+1), stage} above MFMA(k)
  //     so the LDS drain overlaps the matrix-pipe work.
  for (int kk = 0; kk < nk; kk += 4) {
#pragma unroll
    for (int u = 0; u < 4; ++u) {
      const int k = kk + u;
      const int nxtbuf = (u + 1) & 3;          // (k+1)&3, kk%4==0
      const int sbuf = (u + 3) & 3;
      const int kt = (k + 3 < nk) ? (k + 3) : (nk - 1);

      if ((u & 1) == 0) {
        READF(A1, B1, nxtbuf);                 // frags for tile k+1
        STAGE(kt, sbuf);
        __builtin_amdgcn_sched_barrier(0);     // keep reads/stage above MFMA
        MFMA32(A0, B0);                        // compute tile k
      } else {
        READF(A0, B0, nxtbuf);
        STAGE(kt, sbuf);
        __builtin_amdgcn_sched_barrier(0);
        MFMA32(A1, B1);
      }
      asm volatile("s_waitcnt vmcnt(4)" ::: "memory");  // stage(k+2) complete
      __builtin_amdgcn_s_barrier();
    }
  }

  // --- epilogue: C/D layout col=lane&15, row=(lane>>4)*4+reg
  const int crow0 = m0 + wr * 128 + (lane >> 4) * 4;
  const int ccol0 = n0 + wc * 64 + l15;
#pragma unroll
  for (int mi = 0; mi < 8; ++mi)
#pragma unroll
    for (int ni = 0; ni < 4; ++ni) {
      float* Cp = C + (size_t)(crow0 + mi * 16) * DIM_N + ccol0 + ni * 16;
#pragma unroll
      for (int r2 = 0; r2 < 4; ++r2) Cp[(size_t)r2 * DIM_N] = acc[mi][ni][r2];
    }
#undef AFRAG
#undef BFRAG
#undef STAGE
#undef READF
#undef MFMA32
}

extern "C" void kernel_launch(void* const* d_in, const int* in_sizes, int n_in,
                              void* d_out, int out_size, void* d_ws,
                              size_t ws_size, hipStream_t stream) {
  const float* x = (const float*)d_in[0];
  const float* W = (const float*)d_in[1];
  float* out = (float*)d_out;

  unsigned short* xb = (unsigned short*)d_ws;                  // 64 MB
  unsigned short* wt = xb + (size_t)M_TOK * DIM_K;             // 32 MB

  cvt_x_kernel<<<2048, 256, 0, stream>>>(x, xb, M_TOK * DIM_K / 4);
  cvt_wt_kernel<<<dim3(DIM_K / 32, DIM_N / 32), dim3(32, 8), 0, stream>>>(W, wt);
  gemm_kernel<<<512, 512, 0, stream>>>(xb, wt, out);
}